// Round 5
// baseline (41.805 us; speedup 1.0000x reference)
//
#include <hip/hip_runtime.h>

#define D   256
#define NB  128
#define NV  53
#define NR  8192            // rows per side (64*128)
#define V4  14              // v-groups of 4 (56 slots)
#define SLB (V4*NR*4)       // 458752 ushorts per slice
#define WBOFF (4*SLB)       // ushort offset of fragment-ordered W (3584*8 ushorts)
#define BTOFF (WBOFF + 3584*8)  // ushort offset of bias table (112 floats)
#define LOG2E 1.44269504088896340736f
#define LN2   0.69314718055994530942f

// ws (ushort units): PS @0, PI @SLB, MS @2*SLB, MI @3*SLB, WBg @WBOFF, biasT @BTOFF
// slice element (v, row) at ((v>>2)*NR + row)*4 + (v&3); values are bf16 of
// (logit*log2e - rowmax_of_class); slots 53..55 hold -1e30 pads.

typedef float  f4 __attribute__((ext_vector_type(4)));
typedef float  f2 __attribute__((ext_vector_type(2)));
typedef short  s8 __attribute__((ext_vector_type(8)));

__device__ __forceinline__ ushort f2bf(float f) {            // RNE f32 -> bf16
    uint u = __float_as_uint(f);
    u += 0x7fff + ((u >> 16) & 1);
    return (ushort)(u >> 16);
}
__device__ __forceinline__ float bflo(uint w) { return __uint_as_float(w << 16); }
__device__ __forceinline__ float bfhi(uint w) { return __uint_as_float(w & 0xffff0000u); }

__device__ __forceinline__ float fexp2(float x) {
#if __has_builtin(__builtin_amdgcn_exp2f)
    return __builtin_amdgcn_exp2f(x);
#else
    return exp2f(x);
#endif
}
__device__ __forceinline__ float flog2(float x) {
#if __has_builtin(__builtin_amdgcn_logf)
    return __builtin_amdgcn_logf(x);
#else
    return log2f(x);
#endif
}

// ---- p0: W -> fragment-ordered bf16 (scaled by log2e) + scaled bias table ----
__global__ void p0_kernel(const float* __restrict__ Wsub, const float* __restrict__ Wins,
                          const float* __restrict__ bsub, const float* __restrict__ bins,
                          ushort* __restrict__ WBg, float* __restrict__ biasT)
{
    const int F  = blockIdx.x * 64 + threadIdx.x;   // fragment slot 0..3583
    const int l  = F & 63, s = (F >> 6) & 7, nt = F >> 9;
    const int o  = nt * 16 + (l & 15);
    const int d0 = 32 * s + 8 * (l >> 4);
    s8 bfr;
    if (o < NV) {
        const float* w = Wsub + o * D + d0;
        #pragma unroll
        for (int j = 0; j < 8; ++j) bfr[j] = (short)f2bf(w[j] * LOG2E);
    } else if (o < 106) {
        const float* w = Wins + (o - NV) * D + d0;
        #pragma unroll
        for (int j = 0; j < 8; ++j) bfr[j] = (short)f2bf(w[j] * LOG2E);
    } else {
        #pragma unroll
        for (int j = 0; j < 8; ++j) bfr[j] = 0;
    }
    *(s8*)&WBg[F * 8] = bfr;
    if (F < 112) {
        float bv = 0.f;
        if (F < NV)       bv = bsub[F] * LOG2E;
        else if (F < 106) bv = bins[F - NV] * LOG2E;
        biasT[F] = bv;
    }
}

// ---- p1: MFMA GEMM, B streamed from global WBg (no LDS, no barrier), ----
// ---- epilogue computes per-row class maxes and stores max-subtracted bf16 ----
__global__ __launch_bounds__(256, 1) void p1_kernel(
    const float* __restrict__ prior, const float* __restrict__ modern,
    const ushort* __restrict__ WBg, const float* __restrict__ biasT,
    ushort* __restrict__ wsb)
{
    const int tid  = threadIdx.x;
    const int wave = tid >> 6, lane = tid & 63;
    const int tile = blockIdx.x * 4 + wave;           // 0..1023
    const int side = tile >> 9;                       // 0: prior, 1: modern
    const int row0 = (tile & 511) << 4;
    const int lrow = lane & 15, lk = lane >> 4;
    const float* __restrict__ src =
        (side ? modern : prior) + (size_t)(row0 + lrow) * D + lk * 8;

    f4 acc[7];
    #pragma unroll
    for (int nt = 0; nt < 7; ++nt) { acc[nt][0]=0.f; acc[nt][1]=0.f; acc[nt][2]=0.f; acc[nt][3]=0.f; }

    #pragma unroll
    for (int s = 0; s < 8; ++s) {
        const f4 c0 = *(const f4*)(src + 32 * s);
        const f4 c1 = *(const f4*)(src + 32 * s + 4);
        s8 a;
        a[0]=(short)f2bf(c0[0]); a[1]=(short)f2bf(c0[1]);
        a[2]=(short)f2bf(c0[2]); a[3]=(short)f2bf(c0[3]);
        a[4]=(short)f2bf(c1[0]); a[5]=(short)f2bf(c1[1]);
        a[6]=(short)f2bf(c1[2]); a[7]=(short)f2bf(c1[3]);
        #pragma unroll
        for (int nt = 0; nt < 7; ++nt) {
            const s8 bfr = *(const s8*)&WBg[(((nt << 3) + s) * 64 + lane) * 8];
            acc[nt] = __builtin_amdgcn_mfma_f32_16x16x32_bf16(a, bfr, acc[nt], 0, 0, 0);
        }
    }

    // biased values (scaled space)
    float val[7][4];
    #pragma unroll
    for (int nt = 0; nt < 7; ++nt) {
        const int v = nt * 16 + lrow;
        const float bias = side ? biasT[v] : 0.f;
        #pragma unroll
        for (int r = 0; r < 4; ++r) val[nt][r] = acc[nt][r] + bias;
    }

    // per-row maxes for sub (v<53) and ins (53..105) classes
    float ms[4], mi[4];
    #pragma unroll
    for (int r = 0; r < 4; ++r) { ms[r] = -3e38f; mi[r] = -3e38f; }
    #pragma unroll
    for (int nt = 0; nt < 7; ++nt) {
        const int v = nt * 16 + lrow;
        const bool isS = v < NV;
        const bool isI = (v >= NV) & (v < 106);
        #pragma unroll
        for (int r = 0; r < 4; ++r) {
            ms[r] = fmaxf(ms[r], isS ? val[nt][r] : -3e38f);
            mi[r] = fmaxf(mi[r], isI ? val[nt][r] : -3e38f);
        }
    }
    #pragma unroll
    for (int r = 0; r < 4; ++r) {
        #pragma unroll
        for (int k = 1; k <= 8; k <<= 1) {
            ms[r] = fmaxf(ms[r], __shfl_xor(ms[r], k));
            mi[r] = fmaxf(mi[r], __shfl_xor(mi[r], k));
        }
    }

    // C/D: col(v) = nt*16 + lrow, row = row0 + 4*lk + reg
    ushort* __restrict__ base = wsb + side * (2 * SLB);
    #pragma unroll
    for (int nt = 0; nt < 7; ++nt) {
        const int v = nt * 16 + lrow;
        if (v < 106) {
            const bool isS = v < NV;
            const int  vi  = isS ? v : v - NV;
            ushort* sl     = base + (isS ? 0 : SLB);
            const int a0   = (vi >> 2) * (NR * 4) + (vi & 3);
            #pragma unroll
            for (int r = 0; r < 4; ++r) {
                const int row = row0 + 4 * lk + r;
                const float rm = isS ? ms[r] : mi[r];
                sl[a0 + row * 4] = f2bf(val[nt][r] - rm);
            }
        }
    }
    // pads: slots 53..55 of both slices <- -1e30 (lanes v=106..108, i.e. nt=6 lrow 10..12)
    {
        const int v6 = 96 + lrow;
        if (v6 >= 106 && v6 <= 108) {
            const int vi = v6 - NV;                      // 53..55
            const int a0 = (vi >> 2) * (NR * 4) + (vi & 3);
            const ushort PADBF = f2bf(-1e30f);
            #pragma unroll
            for (int r = 0; r < 4; ++r) {
                const int row = row0 + 4 * lk + r;
                base[a0 + row * 4]       = PADBF;
                base[SLB + a0 + row * 4] = PADBF;
            }
        }
    }
}

// ---- p2: lse = log2(sum exp2(P'' + M'')); packed adds; no max pass ----
__global__ __launch_bounds__(256, 2) void p2_kernel(
    const ushort* __restrict__ wsb,
    const int* __restrict__ target, const int* __restrict__ srclen,
    const int* __restrict__ tgtlen, float* __restrict__ out)
{
    const int tid = threadIdx.x;
    const int b   = tid & 127;
    const int bid = blockIdx.x;
    const int xt  = ((bid & 7) << 1) | ((bid >> 3) & 1);   // 0..15 (XCD spread)
    const int y   = ((bid >> 4) << 1) | (tid >> 7);        // 0..63
    const int yb  = y * NB + b;

    const int sl = srclen[b], tl = tgtlen[b];
    const bool ymask = y < tl;
    const bool hasT  = y < 63;
    const int  t     = hasT ? target[y * NB + b] : 0;
    const int  toff  = (t >> 2) * (NR * 4) + (t & 3);

    #pragma unroll
    for (int dist = 0; dist < 2; ++dist) {                 // 0: sub, 1: ins
        const ushort* __restrict__ P = wsb + dist * SLB;
        const ushort* __restrict__ M = wsb + (2 + dist) * SLB;

        f2 Ml[V4], Mh[V4];
        #pragma unroll
        for (int g = 0; g < V4; ++g) {
            const uint2 q = *(const uint2*)(M + (g * NR + yb) * 4);
            Ml[g][0] = bflo(q.x); Ml[g][1] = bfhi(q.x);
            Mh[g][0] = bflo(q.y); Mh[g][1] = bfhi(q.y);
        }
        const float mlt = bflo((uint)M[toff + yb * 4]);

        float* __restrict__ o0 = out + dist * 524288;              // del / end
        float* __restrict__ o1 = out + 1048576 + dist * 516096;    // sub_probs / ins_probs

        #pragma unroll
        for (int xi = 0; xi < 4; ++xi) {
            const int x  = (xt << 2) + xi;
            const int xb = x * NB + b;
            const bool msk = (x < sl) & ymask;

            f2 sa; sa[0] = 0.f; sa[1] = 0.f;
            f2 sb; sb[0] = 0.f; sb[1] = 0.f;
            float l52 = 0.f;
            #pragma unroll
            for (int g = 0; g < V4; ++g) {
                const uint2 p = *(const uint2*)(P + (g * NR + xb) * 4);
                f2 av; av[0] = bflo(p.x); av[1] = bfhi(p.x);
                f2 bv; bv[0] = bflo(p.y); bv[1] = bfhi(p.y);
                av = av + Ml[g];
                bv = bv + Mh[g];
                if (g == 13) l52 = av[0];                  // v = 52
                f2 ea; ea[0] = fexp2(av[0]); ea[1] = fexp2(av[1]);
                f2 eb; eb[0] = fexp2(bv[0]); eb[1] = fexp2(bv[1]);
                sa = sa + ea;
                sb = sb + eb;
            }
            const f2 st = sa + sb;
            const float ls = flog2(st[0] + st[1]);
            o0[((x << 6) | y) * NB + b] = msk ? (l52 - ls) * LN2 : 0.f;
            if (hasT) {
                const float lt = bflo((uint)P[toff + xb * 4]) + mlt;
                o1[(x * 63 + y) * NB + b] = msk ? (lt - ls) * LN2 : 0.f;
            }
        }
    }
}

extern "C" void kernel_launch(void* const* d_in, const int* in_sizes, int n_in,
                              void* d_out, int out_size, void* d_ws, size_t ws_size,
                              hipStream_t stream) {
    const float* prior  = (const float*)d_in[0];
    const float* modern = (const float*)d_in[1];
    const float* Wsub   = (const float*)d_in[2];
    const float* bsub   = (const float*)d_in[3];
    const float* Wins   = (const float*)d_in[4];
    const float* bins   = (const float*)d_in[5];
    const int*   target = (const int*)d_in[6];
    const int*   srclen = (const int*)d_in[7];
    const int*   tgtlen = (const int*)d_in[8];
    ushort* wsb   = (ushort*)d_ws;
    ushort* WBg   = wsb + WBOFF;
    float*  biasT = (float*)(wsb + BTOFF);
    float*  out   = (float*)d_out;

    p0_kernel<<<56, 64, 0, stream>>>(Wsub, Wins, bsub, bins, WBg, biasT);
    p1_kernel<<<256, 256, 0, stream>>>(prior, modern, WBg, biasT, wsb);
    p2_kernel<<<512, 256, 0, stream>>>(wsb, target, srclen, tgtlen, out);
}

// Round 6
// 38.067 us; speedup vs baseline: 1.0982x; 1.0982x over previous
//
#include <hip/hip_runtime.h>

#define D   256
#define NB  128
#define NV  53
#define NR  8192            // rows per side (64*128)
#define V4  14              // v-groups of 4 (56 slots)
#define SLB (V4*NR*4)       // 458752 ushorts per slice
#define ESOFF (4*SLB)       // E (exp2) slices start here
#define WBOFF (8*SLB)       // fragment-ordered W (3584*8 ushorts)
#define BTOFF (WBOFF + 3584*8)  // bias table (112 floats)
#define A52   (13*NR*4)     // slice offset of v-slot 52 (group 13, sub 0)
#define LOG2E 1.44269504088896340736f
#define LN2   0.69314718055994530942f

// ws (ushort units): raw slices PS@0 PI@SLB MS@2SLB MI@3SLB (bf16 of logit*log2e,
// bias folded into modern side); E slices = exp2(raw) at +ESOFF, same layout,
// pad slots 53..55 zeroed; WBg @WBOFF; biasT @BTOFF.
// slice element (v, row) at ((v>>2)*NR + row)*4 + (v&3)

typedef float  f4 __attribute__((ext_vector_type(4)));
typedef float  f2 __attribute__((ext_vector_type(2)));
typedef short  s8 __attribute__((ext_vector_type(8)));

__device__ __forceinline__ ushort f2bf(float f) {            // RNE f32 -> bf16
    uint u = __float_as_uint(f);
    u += 0x7fff + ((u >> 16) & 1);
    return (ushort)(u >> 16);
}
__device__ __forceinline__ float bflo(uint w) { return __uint_as_float(w << 16); }
__device__ __forceinline__ float bfhi(uint w) { return __uint_as_float(w & 0xffff0000u); }
__device__ __forceinline__ float fexp2(float x) { return __builtin_exp2f(x); }
__device__ __forceinline__ float flog2(float x) { return __builtin_log2f(x); }

// ---- p0: W -> fragment-ordered bf16 (scaled by log2e) + scaled bias table ----
__global__ void p0_kernel(const float* __restrict__ Wsub, const float* __restrict__ Wins,
                          const float* __restrict__ bsub, const float* __restrict__ bins,
                          ushort* __restrict__ WBg, float* __restrict__ biasT)
{
    const int F  = blockIdx.x * 64 + threadIdx.x;   // fragment slot 0..3583
    const int l  = F & 63, s = (F >> 6) & 7, nt = F >> 9;
    const int o  = nt * 16 + (l & 15);
    const int d0 = 32 * s + 8 * (l >> 4);
    s8 bfr;
    if (o < NV) {
        const float* w = Wsub + o * D + d0;
        #pragma unroll
        for (int j = 0; j < 8; ++j) bfr[j] = (short)f2bf(w[j] * LOG2E);
    } else if (o < 106) {
        const float* w = Wins + (o - NV) * D + d0;
        #pragma unroll
        for (int j = 0; j < 8; ++j) bfr[j] = (short)f2bf(w[j] * LOG2E);
    } else {
        #pragma unroll
        for (int j = 0; j < 8; ++j) bfr[j] = 0;
    }
    *(s8*)&WBg[F * 8] = bfr;
    if (F < 112) {
        float bv = 0.f;
        if (F < NV)       bv = bsub[F] * LOG2E;
        else if (F < 106) bv = bins[F - NV] * LOG2E;
        biasT[F] = bv;
    }
}

// ---- p1: MFMA GEMM; W staged coalesced WBg->LDS; nt-tiles split across 2 blocks ----
template<int NT0, int NTN>
__device__ __forceinline__ void p1_body(
    const float* __restrict__ prior, const float* __restrict__ modern,
    const ushort* __restrict__ WBg, const float* __restrict__ biasT,
    ushort* __restrict__ wsb, ushort* __restrict__ WB, int tid, int tg)
{
    // stage NTN*512 fragment slots (16 B each), fully coalesced
    #pragma unroll
    for (int i = 0; i < NTN * 2; ++i) {
        const int idx = i * 256 + tid;
        *(s8*)&WB[idx * 8] = *(const s8*)&WBg[(NT0 * 512 + idx) * 8];
    }
    __syncthreads();

    const int wave = tid >> 6, lane = tid & 63;
    const int tile = tg * 4 + wave;                  // 0..1023
    const int side = tile >> 9;                      // 0: prior, 1: modern
    const int row0 = (tile & 511) << 4;
    const int lrow = lane & 15, lk = lane >> 4;
    const float* __restrict__ src =
        (side ? modern : prior) + (size_t)(row0 + lrow) * D + lk * 8;

    f4 acc[NTN];
    #pragma unroll
    for (int j = 0; j < NTN; ++j) { acc[j][0]=0.f; acc[j][1]=0.f; acc[j][2]=0.f; acc[j][3]=0.f; }

    #pragma unroll
    for (int s = 0; s < 8; ++s) {
        const f4 c0 = *(const f4*)(src + 32 * s);
        const f4 c1 = *(const f4*)(src + 32 * s + 4);
        s8 a;
        a[0]=(short)f2bf(c0[0]); a[1]=(short)f2bf(c0[1]);
        a[2]=(short)f2bf(c0[2]); a[3]=(short)f2bf(c0[3]);
        a[4]=(short)f2bf(c1[0]); a[5]=(short)f2bf(c1[1]);
        a[6]=(short)f2bf(c1[2]); a[7]=(short)f2bf(c1[3]);
        #pragma unroll
        for (int j = 0; j < NTN; ++j) {
            const s8 bfr = *(const s8*)&WB[(((j << 3) + s) * 64 + lane) * 8];
            acc[j] = __builtin_amdgcn_mfma_f32_16x16x32_bf16(a, bfr, acc[j], 0, 0, 0);
        }
    }

    // epilogue: raw bf16 + E = exp2(raw) bf16, no max pass
    #pragma unroll
    for (int j = 0; j < NTN; ++j) {
        const int v = (NT0 + j) * 16 + lrow;         // <= 111
        const float bias = side ? biasT[v] : 0.f;
        const bool valid = v < 106;
        const bool isS   = v < NV;
        const int  vi    = isS ? v : v - NV;
        ushort* __restrict__ raw = wsb + (size_t)(side * 2 + (isS ? 0 : 1)) * SLB;
        ushort* __restrict__ Eb  = raw + ESOFF;
        const int a0 = (vi >> 2) * (NR * 4) + (vi & 3);
        #pragma unroll
        for (int r = 0; r < 4; ++r) {
            if (valid) {
                const int row = row0 + 4 * lk + r;
                const float val = acc[j][r] + bias;
                raw[a0 + row * 4] = f2bf(val);
                Eb[a0 + row * 4]  = f2bf(fexp2(val));
            }
        }
    }
    // E pad slots 53..55 <- 0 (written by the NT0==4 half, lanes lrow 10..12)
    if (NT0 == 4) {
        if (lrow >= 10 && lrow <= 12) {
            const int vi = 43 + lrow;                // 53..55
            const int a0 = (vi >> 2) * (NR * 4) + (vi & 3);
            #pragma unroll
            for (int r = 0; r < 4; ++r) {
                const int row = row0 + 4 * lk + r;
                wsb[ESOFF + (size_t)(side * 2 + 0) * SLB + a0 + row * 4] = 0;
                wsb[ESOFF + (size_t)(side * 2 + 1) * SLB + a0 + row * 4] = 0;
            }
        }
    }
}

__global__ __launch_bounds__(256) void p1_kernel(
    const float* __restrict__ prior, const float* __restrict__ modern,
    const ushort* __restrict__ WBg, const float* __restrict__ biasT,
    ushort* __restrict__ wsb)
{
    __shared__ ushort WB[4 * 512 * 8];               // 32 KB
    const int tid = threadIdx.x;
    const int tg  = blockIdx.x >> 1;
    if ((blockIdx.x & 1) == 0)
        p1_body<0, 4>(prior, modern, WBg, biasT, wsb, WB, tid, tg);
    else
        p1_body<4, 3>(prior, modern, WBg, biasT, wsb, WB, tid, tg);
}

// ---- p2: S = dot(EP, EM) over 56 slots (pads 0); lse = log2 S; no exp in loop ----
__global__ __launch_bounds__(256) void p2_kernel(
    const ushort* __restrict__ wsb,
    const int* __restrict__ target, const int* __restrict__ srclen,
    const int* __restrict__ tgtlen, float* __restrict__ out)
{
    const int tid = threadIdx.x;
    const int b   = tid & 127;
    const int bid = blockIdx.x;
    const int xt  = ((bid & 7) << 1) | ((bid >> 3) & 1);   // 0..15 (XCD spread)
    const int y   = ((bid >> 4) << 1) | (tid >> 7);        // 0..63
    const int yb  = y * NB + b;

    const int sl = srclen[b], tl = tgtlen[b];
    const bool ymask = y < tl;
    const bool hasT  = y < 63;
    const int  t     = hasT ? target[y * NB + b] : 0;
    const int  toff  = (t >> 2) * (NR * 4) + (t & 3);

    #pragma unroll 1
    for (int dist = 0; dist < 2; ++dist) {                 // 0: sub, 1: ins
        const ushort* __restrict__ Praw = wsb + dist * SLB;
        const ushort* __restrict__ Mraw = wsb + (2 + dist) * SLB;
        const ushort* __restrict__ PE   = Praw + ESOFF;
        const ushort* __restrict__ ME   = Mraw + ESOFF;

        f2 em0[V4], em1[V4];
        #pragma unroll
        for (int g = 0; g < V4; ++g) {
            const uint2 q = *(const uint2*)(ME + (g * NR + yb) * 4);
            em0[g][0] = bflo(q.x); em0[g][1] = bfhi(q.x);
            em1[g][0] = bflo(q.y); em1[g][1] = bfhi(q.y);
        }
        const float mlt = bflo((uint)Mraw[toff + yb * 4]);
        const float m52 = bflo((uint)Mraw[A52  + yb * 4]);

        float* __restrict__ o0 = out + dist * 524288;              // del / end
        float* __restrict__ o1 = out + 1048576 + dist * 516096;    // sub_probs / ins_probs

        #pragma unroll
        for (int xi = 0; xi < 4; ++xi) {
            const int x  = (xt << 2) + xi;
            const int xb = x * NB + b;
            const bool msk = (x < sl) & ymask;

            f2 s0; s0[0] = 0.f; s0[1] = 0.f;
            f2 s1; s1[0] = 0.f; s1[1] = 0.f;
            #pragma unroll
            for (int g = 0; g < V4; ++g) {
                const uint2 p = *(const uint2*)(PE + (g * NR + xb) * 4);
                f2 a; a[0] = bflo(p.x); a[1] = bfhi(p.x);
                f2 c; c[0] = bflo(p.y); c[1] = bfhi(p.y);
                s0 += a * em0[g];
                s1 += c * em1[g];
            }
            const float S  = (s0[0] + s0[1]) + (s1[0] + s1[1]);
            const float ls = flog2(S);

            const float l52 = bflo((uint)Praw[A52 + xb * 4]) + m52;
            o0[((x << 6) | y) * NB + b] = msk ? (l52 - ls) * LN2 : 0.f;
            if (hasT) {
                const float lt = bflo((uint)Praw[toff + xb * 4]) + mlt;
                o1[(x * 63 + y) * NB + b] = msk ? (lt - ls) * LN2 : 0.f;
            }
        }
    }
}

extern "C" void kernel_launch(void* const* d_in, const int* in_sizes, int n_in,
                              void* d_out, int out_size, void* d_ws, size_t ws_size,
                              hipStream_t stream) {
    const float* prior  = (const float*)d_in[0];
    const float* modern = (const float*)d_in[1];
    const float* Wsub   = (const float*)d_in[2];
    const float* bsub   = (const float*)d_in[3];
    const float* Wins   = (const float*)d_in[4];
    const float* bins   = (const float*)d_in[5];
    const int*   target = (const int*)d_in[6];
    const int*   srclen = (const int*)d_in[7];
    const int*   tgtlen = (const int*)d_in[8];
    ushort* wsb   = (ushort*)d_ws;
    ushort* WBg   = wsb + WBOFF;
    float*  biasT = (float*)(wsb + BTOFF);
    float*  out   = (float*)d_out;

    p0_kernel<<<56, 64, 0, stream>>>(Wsub, Wins, bsub, bins, WBg, biasT);
    p1_kernel<<<512, 256, 0, stream>>>(prior, modern, WBg, biasT, wsb);
    p2_kernel<<<512, 256, 0, stream>>>(wsb, target, srclen, tgtlen, out);
}